// Round 15
// baseline (629.362 us; speedup 1.0000x reference)
//
#include <hip/hip_runtime.h>
#include <cstddef>
#include <cstdint>
#include <cmath>

#define TAU_INV 20.0f
#define NMAT 36
#define BATCH 512
#define MROWS 18432   // 512 * 36
#define MHALF 9216

typedef unsigned short us16;
typedef __attribute__((ext_vector_type(8))) short s16x8;   // 8 bf16 = 4 VGPRs
typedef __attribute__((ext_vector_type(4))) float f32x4;

// ---------------- bf16 helpers (RNE) ----------------
__device__ inline us16 f2bf(float x) {
    uint32_t u = __float_as_uint(x);
    u += 0x7fff + ((u >> 16) & 1);
    return (us16)(u >> 16);
}
__device__ inline float bf2f(us16 h) {
    return __uint_as_float(((uint32_t)h) << 16);
}
// 3-way split (weights pre-split kernel; gemm uses only h,m planes)
__device__ inline void split3(float v, us16& h, us16& m, us16& l) {
    h = f2bf(v);
    float r1 = v - bf2f(h);
    m = f2bf(r1);
    l = f2bf(r1 - bf2f(m));
}

// packed f32x2 -> bf16x2 convert (T12 recipe; no builtin on gfx950)
__device__ inline uint32_t cvtpk(float lo, float hi) {
    uint32_t d;
    asm("v_cvt_pk_bf16_f32 %0, %1, %2" : "=v"(d) : "v"(lo), "v"(hi));
    return d;
}
// 2-way split of 4 floats into packed h/m bf16 plane words.
// 4-tier product (h+m)(h+m) is exact; dropped x*yl+xl*y ~2^-18 rel
// (verified harmless at output precision, R12: absmax unchanged).
__device__ inline void split2pk(const float4& v, uint2& h, uint2& m) {
    uint32_t h0 = cvtpk(v.x, v.y), h1 = cvtpk(v.z, v.w);
    float a0 = v.x - __uint_as_float(h0 << 16);
    float a1 = v.y - __uint_as_float(h0 & 0xffff0000u);
    float a2 = v.z - __uint_as_float(h1 << 16);
    float a3 = v.w - __uint_as_float(h1 & 0xffff0000u);
    uint32_t m0 = cvtpk(a0, a1), m1 = cvtpk(a2, a3);
    h = make_uint2(h0, h1); m = make_uint2(m0, m1);
}

// ---------------- async global->LDS 16B DMA ----------------
__device__ inline void dma16(const void* g, void* l) {
    __builtin_amdgcn_global_load_lds(
        (const __attribute__((address_space(1))) void*)g,
        (__attribute__((address_space(3))) void*)l, 16, 0, 0);
}

__device__ inline f32x4 mfma16(s16x8 a, s16x8 b, f32x4 c) {
    return __builtin_amdgcn_mfma_f32_16x16x32_bf16(a, b, c, 0, 0, 0);
}

// ---------------------------------------------------------------------------
// 2-plane-split bf16 MFMA GEMM:  C = act(X @ W^T + bias)
//   4 tiers (hh,hm,mh,mm); R12-verified numerically at output precision.
// k-loop (R11/R12-proven): barrier -> DMA-B issue -> A-prefetch issue ->
//   split-VALU (covers load latency) -> barrier -> MFMA.
// R12 decomposition: vis1 = ~139 us work + ~89 us latency; latency shrinks
// with TLP (R5/R9) -> vis1 uses <64,128> (24KB LDS, 1152 blocks = 4.5/CU).
// LDS swizzle (verified R3: SQ_LDS_BANK_CONFLICT = 0): us16 idx =
//   row*32 + ((slot8 ^ ((row>>1)&3))*8 + e); A swizzled write+read;
//   B linear DMA dest + pre-swizzled global source col + swizzled read.
// Triple-param-set: blockIdx.z in {0,1,2} selects set (R13: co-schedules
// txt+sen+vis2 in ONE dispatch, 864 blocks; pass dups for unused sets).
// OUT: 0 = relu; 1 = tanh with col<nreal store guard.
// 256 threads = 4 waves, 2x2 wave grid; wave tile (BM/2)x(BN/2).
// ---------------------------------------------------------------------------
template<int BM, int BN, int OUT, int MINW>
__global__ __launch_bounds__(256, MINW)
void gemm_split(int ldc, int nreal, int K,
                const float* X0, int ldx0, const us16* Bh0, const us16* Bm0,
                const float* bias0, float* C0,
                const float* X1, int ldx1, const us16* Bh1, const us16* Bm1,
                const float* bias1, float* C1,
                const float* X2, int ldx2, const us16* Bh2, const us16* Bm2,
                const float* bias2, float* C2)
{
    constexpr int MT  = BM / 32;      // 16-row m-tiles per wave
    constexpr int NT  = BN / 32;      // 16-col n-tiles per wave
    constexpr int NF4 = BM / 32;      // float4 A-loads per thread per k-tile
    constexpr int LB  = BN / 64;      // B DMA chunks per wave per plane

    const float* X; int ldx; const us16 *Bh, *Bm; const float* bias; float* C;
    if (blockIdx.z == 0)      { X = X0; ldx = ldx0; Bh = Bh0; Bm = Bm0; bias = bias0; C = C0; }
    else if (blockIdx.z == 1) { X = X1; ldx = ldx1; Bh = Bh1; Bm = Bm1; bias = bias1; C = C1; }
    else                      { X = X2; ldx = ldx2; Bh = Bh2; Bm = Bm2; bias = bias2; C = C2; }

    alignas(16) __shared__ us16 lds[(BM + BN) * 64];
    us16* AsH = lds;
    us16* AsM = lds + BM * 32;
    us16* BsH = lds + BM * 64;
    us16* BsM = lds + BM * 64 + BN * 32;

    const int tid  = threadIdx.x;
    const int lane = tid & 63;
    const int wid  = tid >> 6;
    const int bm   = blockIdx.x * BM;
    const int bn   = blockIdx.y * BN;
    const int lm   = lane & 15;       // fragment row/col within 16
    const int kb   = lane >> 4;       // k-quad 0..3
    const int wm   = (wid >> 1) * (BM / 2);
    const int wn   = (wid & 1) * (BN / 2);

    // A staging map: thread covers rows arow + i*32, cols acol..acol+3
    const int arow = tid >> 3;        // 0..31
    const int acol = (tid & 7) * 4;   // 0,4,..,28
    const int asw  = ((arow >> 1) & 3) << 3;   // A write swizzle (us16 idx bits 3-4)
    const int fsw  = ((lm >> 1) & 3) << 3;     // fragment read swizzle

    f32x4 acc[MT][NT];
#pragma unroll
    for (int i = 0; i < MT; ++i)
#pragma unroll
        for (int j = 0; j < NT; ++j) acc[i][j] = (f32x4){0.f, 0.f, 0.f, 0.f};

    float4 pref[NF4];
#pragma unroll
    for (int i = 0; i < NF4; ++i)
        pref[i] = *(const float4*)(X + (size_t)(bm + i * 32 + arow) * ldx + acol);

    // B DMA: linear dest (wave-uniform base + lane*16B), pre-swizzled src col
    const int bcol = ((lane & 3) ^ ((lane >> 3) & 3)) * 8;

    for (int k0 = 0; k0 < K; k0 += 32) {
        __syncthreads();   // previous compute done; LDS reusable
        // ---- hoisted: async DMA B tile (2 planes) — flies under the split ----
#pragma unroll
        for (int q = 0; q < LB; ++q) {
            const int rb = wid * (LB * 16) + q * 16;          // wave-uniform
            const int gr = bn + rb + (lane >> 2);
            const int gc = k0 + bcol;
            dma16(Bh + (size_t)gr * K + gc, &BsH[rb * 32]);
            dma16(Bm + (size_t)gr * K + gc, &BsM[rb * 32]);
        }
        // ---- hoisted: A prefetch for next k-tile (ping-pong regs) ----
        float4 prefN[NF4];
        if (k0 + 32 < K) {
#pragma unroll
            for (int i = 0; i < NF4; ++i)
                prefN[i] = *(const float4*)(X + (size_t)(bm + i * 32 + arow) * ldx
                                            + (k0 + 32) + acol);
        }
        // ---- split current A into h/m LDS planes (covers load latency) ----
#pragma unroll
        for (int i = 0; i < NF4; ++i) {
            const int r = i * 32 + arow;
            uint2 h, m;
            split2pk(pref[i], h, m);
            *(uint2*)&AsH[r * 32 + (acol ^ asw)] = h;
            *(uint2*)&AsM[r * 32 + (acol ^ asw)] = m;
        }
        if (k0 + 32 < K) {
#pragma unroll
            for (int i = 0; i < NF4; ++i) pref[i] = prefN[i];
        }
        __syncthreads();   // staging visible (compiler drains vmcnt+lgkm)

        // ---- MFMA phase: 4 tiers (hh, hm, mh, mm) ----
        s16x8 ah[MT], am[MT];
#pragma unroll
        for (int mt = 0; mt < MT; ++mt) {
            const int off = (wm + mt * 16 + lm) * 32 + (kb * 8 ^ fsw);
            ah[mt] = *(const s16x8*)&AsH[off];
            am[mt] = *(const s16x8*)&AsM[off];
        }
#pragma unroll
        for (int nt = 0; nt < NT; ++nt) {
            const int off = (wn + nt * 16 + lm) * 32 + (kb * 8 ^ fsw);
            s16x8 bfh = *(const s16x8*)&BsH[off];
            s16x8 bfm = *(const s16x8*)&BsM[off];
#pragma unroll
            for (int mt = 0; mt < MT; ++mt) {
                acc[mt][nt] = mfma16(ah[mt], bfh, acc[mt][nt]);
                acc[mt][nt] = mfma16(ah[mt], bfm, acc[mt][nt]);
                acc[mt][nt] = mfma16(am[mt], bfh, acc[mt][nt]);
                acc[mt][nt] = mfma16(am[mt], bfm, acc[mt][nt]);
            }
        }
    }

    // ---- epilogue: bias + activation (C/D map: col=lane&15, row=quad*4+r) ----
    float bv[NT];
#pragma unroll
    for (int nt = 0; nt < NT; ++nt) {
        const int col = bn + wn + nt * 16 + lm;
        bv[nt] = (col < nreal) ? bias[col] : 0.f;
    }
#pragma unroll
    for (int nt = 0; nt < NT; ++nt) {
        const int col = bn + wn + nt * 16 + lm;
#pragma unroll
        for (int mt = 0; mt < MT; ++mt) {
#pragma unroll
            for (int r = 0; r < 4; ++r) {
                const int row = bm + wm + mt * 16 + kb * 4 + r;
                float v = acc[mt][nt][r] + bv[nt];
                if (OUT == 0) {
                    C[(size_t)row * ldc + col] = fmaxf(v, 0.f);
                } else {
                    if (col < nreal)
                        C[(size_t)row * ldc + col] = tanhf(v);
                }
            }
        }
    }
}

// ---------------------------------------------------------------------------
// Weight pre-split into padded bf16 hi/mid/lo planes (lo unused by gemm).
// Plane layout (ushort offsets): w1v [512x2048] @0, w1t @1048576, w1s @1114112,
// w2v @1179648, wfp [256x416 pad] @1245184, wfc [64x256 pad] @1351680; tot 1368064
// ---------------------------------------------------------------------------
#define WOFF_W1T 1048576
#define WOFF_W1S 1114112
#define WOFF_W2V 1179648
#define WOFF_WFP 1245184
#define WOFF_WFC 1351680
#define WTOT     1368064

__global__ void split_weights(const float* __restrict__ w1v, const float* __restrict__ w1t,
                              const float* __restrict__ w1s, const float* __restrict__ w2v,
                              const float* __restrict__ wfp, const float* __restrict__ wfc,
                              us16* __restrict__ hi, us16* __restrict__ mi,
                              us16* __restrict__ lo)
{
    int idx = blockIdx.x * 256 + threadIdx.x;
    if (idx >= WTOT) return;
    const float* src; int N, K, Kp; int local;
    if (idx < WOFF_W1T)      { src = w1v; N = 512; K = 2048; Kp = 2048; local = idx; }
    else if (idx < WOFF_W1S) { src = w1t; N = 128; K = 512;  Kp = 512;  local = idx - WOFF_W1T; }
    else if (idx < WOFF_W2V) { src = w1s; N = 128; K = 512;  Kp = 512;  local = idx - WOFF_W1S; }
    else if (idx < WOFF_WFP) { src = w2v; N = 128; K = 512;  Kp = 512;  local = idx - WOFF_W2V; }
    else if (idx < WOFF_WFC) { src = wfp; N = 256; K = 388;  Kp = 416;  local = idx - WOFF_WFP; }
    else                     { src = wfc; N = 36;  K = 256;  Kp = 256;  local = idx - WOFF_WFC; }
    int n = local / Kp, k = local % Kp;
    float v = (n < N && k < K) ? src[(size_t)n * K + k] : 0.f;
    us16 h, m, l;
    split3(v, h, m, l);
    hi[idx] = h; mi[idx] = m; lo[idx] = l;
}

// ---------------------------------------------------------------------------
// pos branch + cat K-padding: cat cols [256,260) = relu(pos), [388,416) = 0
// ---------------------------------------------------------------------------
__global__ void pos_pad(const float* __restrict__ seq, float* __restrict__ cat)
{
    int idx = blockIdx.x * 256 + threadIdx.x;
    if (idx >= MROWS * 32) return;
    int row = idx >> 5, j = idx & 31;
    if (j < 4) {
        float v = seq[(size_t)row * 3076 + 2560 + j];
        cat[(size_t)row * 416 + 256 + j] = fmaxf(v, 0.f);
    } else {
        cat[(size_t)row * 416 + 388 + (j - 4)] = 0.f;
    }
}

// ---------------------------------------------------------------------------
// Sinkhorn (verified in R2)
// ---------------------------------------------------------------------------
__global__ __launch_bounds__(256)
void sinkhorn_kernel(const float* __restrict__ Z, float* __restrict__ out)
{
    __shared__ float A[NMAT][NMAT + 1];
    __shared__ float lse[NMAT];
    const int b = blockIdx.x;
    const int tid = threadIdx.x;
    const float* zb = Z + (size_t)b * NMAT * NMAT;

    for (int idx = tid; idx < NMAT * NMAT; idx += 256)
        A[idx / NMAT][idx % NMAT] = expf(zb[idx] * TAU_INV);
    __syncthreads();

    for (int it = 0; it < 20; ++it) {
        if (tid < NMAT * 4) {
            int r = tid >> 2, g = tid & 3;
            float m = -3.402823466e38f;
            for (int j = g; j < NMAT; j += 4) m = fmaxf(m, A[r][j]);
            m = fmaxf(m, __shfl_xor(m, 2, 4));
            m = fmaxf(m, __shfl_xor(m, 1, 4));
            float s = 0.f;
            for (int j = g; j < NMAT; j += 4) s += expf(A[r][j] - m);
            s += __shfl_xor(s, 2, 4);
            s += __shfl_xor(s, 1, 4);
            if (g == 0) lse[r] = m + logf(s);
        }
        __syncthreads();
        for (int idx = tid; idx < NMAT * NMAT; idx += 256)
            A[idx / NMAT][idx % NMAT] -= lse[idx / NMAT];
        __syncthreads();

        if (tid < NMAT * 4) {
            int c = tid >> 2, g = tid & 3;
            float m = -3.402823466e38f;
            for (int i = g; i < NMAT; i += 4) m = fmaxf(m, A[i][c]);
            m = fmaxf(m, __shfl_xor(m, 2, 4));
            m = fmaxf(m, __shfl_xor(m, 1, 4));
            float s = 0.f;
            for (int i = g; i < NMAT; i += 4) s += expf(A[i][c] - m);
            s += __shfl_xor(s, 2, 4);
            s += __shfl_xor(s, 1, 4);
            if (g == 0) lse[c] = m + logf(s);
        }
        __syncthreads();
        for (int idx = tid; idx < NMAT * NMAT; idx += 256)
            A[idx / NMAT][idx % NMAT] -= lse[idx % NMAT];
        __syncthreads();
    }

    for (int idx = tid; idx < NMAT * NMAT; idx += 256)
        out[(size_t)b * NMAT * NMAT + idx] = expf(A[idx / NMAT][idx % NMAT]);
}

// ---------------------------------------------------------------------------
extern "C" void kernel_launch(void* const* d_in, const int* in_sizes, int n_in,
                              void* d_out, int out_size, void* d_ws, size_t ws_size,
                              hipStream_t stream)
{
    const float* seq = (const float*)d_in[0];
    const float* W1t = (const float*)d_in[1];
    const float* b1t = (const float*)d_in[2];
    const float* W1v = (const float*)d_in[3];
    const float* b1v = (const float*)d_in[4];
    const float* W2v = (const float*)d_in[5];
    const float* b2v = (const float*)d_in[6];
    const float* W1s = (const float*)d_in[7];
    const float* b1s = (const float*)d_in[8];
    const float* Wfp = (const float*)d_in[9];
    const float* bfp = (const float*)d_in[10];
    const float* Wfc = (const float*)d_in[11];
    const float* bfc = (const float*)d_in[12];

    float* wsF = (float*)d_ws;
    dim3 blk(256);

    // Full-M layout needs 76.63 MB (R9-R12 verified working); fallback otherwise.
    const bool full = ws_size >= (size_t)19156992 * 4;

    if (full) {
        // ws layout (float offsets), full-M:
        //   [0, 9437184)         : vis1 (18432x512); later h256 (18432x256)
        //   [9437184, 17104896)  : cat (18432x416); later logits
        //   [17104896, +2052096) : weight planes hi/mid/lo (3 x WTOT us16)
        float* vis1buf = wsF;
        float* h256    = wsF;
        float* cat     = wsF + 9437184;
        float* logits  = wsF + 9437184;
        us16*  Whi     = (us16*)(wsF + 17104896);
        us16*  Wmi     = Whi + WTOT;
        us16*  Wlo     = Wmi + WTOT;

        split_weights<<<dim3((WTOT + 255) / 256), blk, 0, stream>>>(
            W1v, W1t, W1s, W2v, Wfp, Wfc, Whi, Wmi, Wlo);
        pos_pad<<<dim3((MROWS * 32 + 255) / 256), blk, 0, stream>>>(seq, cat);
        // vis1: <64,128> 2-plane, grid 288x4 = 1152 blocks (4.5/CU, 24KB LDS)
        gemm_split<64, 128, 0, 4><<<dim3(MROWS / 64, 4, 1), blk, 0, stream>>>(
            512, 512, 2048,
            seq + 512, 3076, Whi, Wmi, b1v, vis1buf,
            seq + 512, 3076, Whi, Wmi, b1v, vis1buf,
            seq + 512, 3076, Whi, Wmi, b1v, vis1buf);
        // txt + sen + vis2 fused in ONE dispatch (z selects set; 864 blocks)
        gemm_split<64, 128, 0, 4><<<dim3(MROWS / 64, 1, 3), blk, 0, stream>>>(
            416, 128, 512,
            seq,        3076, Whi + WOFF_W1T, Wmi + WOFF_W1T, b1t, cat,
            seq + 2564, 3076, Whi + WOFF_W1S, Wmi + WOFF_W1S, b1s, cat + 260,
            vis1buf,    512,  Whi + WOFF_W2V, Wmi + WOFF_W2V, b2v, cat + 128);
        // fc_pos: (M,416)->256 relu -> h256 (overlays vis1buf, now dead)
        gemm_split<64, 128, 0, 4><<<dim3(MROWS / 64, 2, 1), blk, 0, stream>>>(
            256, 256, 416,
            cat, 416, Whi + WOFF_WFP, Wmi + WOFF_WFP, bfp, h256,
            cat, 416, Whi + WOFF_WFP, Wmi + WOFF_WFP, bfp, h256,
            cat, 416, Whi + WOFF_WFP, Wmi + WOFF_WFP, bfp, h256);
        // fc: (M,256)->36 tanh -> logits (overlays cat, now dead)
        gemm_split<64, 64, 1, 4><<<dim3(MROWS / 64, 1, 1), blk, 0, stream>>>(
            36, 36, 256,
            h256, 256, Whi + WOFF_WFC, Wmi + WOFF_WFC, bfc, logits,
            h256, 256, Whi + WOFF_WFC, Wmi + WOFF_WFC, bfc, logits,
            h256, 256, Whi + WOFF_WFC, Wmi + WOFF_WFC, bfc, logits);
        sinkhorn_kernel<<<dim3(BATCH), blk, 0, stream>>>(logits, (float*)d_out);
    } else {
        // ---- half-M fallback (57.8 MB), same 2-plane kernel ----
        float* vis1buf = wsF;
        float* h256    = wsF;
        float* cat     = wsF + 4718592;
        float* logits  = wsF + 4718592;
        us16*  Whi     = (us16*)(wsF + 12386304);
        us16*  Wmi     = Whi + WTOT;
        us16*  Wlo     = Wmi + WTOT;

        split_weights<<<dim3((WTOT + 255) / 256), blk, 0, stream>>>(
            W1v, W1t, W1s, W2v, Wfp, Wfc, Whi, Wmi, Wlo);
        pos_pad<<<dim3((MROWS * 32 + 255) / 256), blk, 0, stream>>>(seq, cat);
        gemm_split<64, 128, 0, 4><<<dim3(MROWS / 64, 1, 2), blk, 0, stream>>>(
            416, 128, 512,
            seq,        3076, Whi + WOFF_W1T, Wmi + WOFF_W1T, b1t, cat,
            seq + 2564, 3076, Whi + WOFF_W1S, Wmi + WOFF_W1S, b1s, cat + 260,
            seq,        3076, Whi + WOFF_W1T, Wmi + WOFF_W1T, b1t, cat);
        for (int h = 0; h < 2; ++h) {
            const float* xh = seq + 512 + (size_t)h * MHALF * 3076;
            float* ch = cat + 128 + (size_t)h * MHALF * 416;
            gemm_split<64, 128, 0, 4><<<dim3(MHALF / 64, 4, 1), blk, 0, stream>>>(
                512, 512, 2048,
                xh, 3076, Whi, Wmi, b1v, vis1buf,
                xh, 3076, Whi, Wmi, b1v, vis1buf,
                xh, 3076, Whi, Wmi, b1v, vis1buf);
            gemm_split<64, 64, 0, 4><<<dim3(MHALF / 64, 2, 1), blk, 0, stream>>>(
                416, 128, 512,
                vis1buf, 512, Whi + WOFF_W2V, Wmi + WOFF_W2V, b2v, ch,
                vis1buf, 512, Whi + WOFF_W2V, Wmi + WOFF_W2V, b2v, ch,
                vis1buf, 512, Whi + WOFF_W2V, Wmi + WOFF_W2V, b2v, ch);
        }
        gemm_split<64, 128, 0, 4><<<dim3(MROWS / 64, 2, 1), blk, 0, stream>>>(
            256, 256, 416,
            cat, 416, Whi + WOFF_WFP, Wmi + WOFF_WFP, bfp, h256,
            cat, 416, Whi + WOFF_WFP, Wmi + WOFF_WFP, bfp, h256,
            cat, 416, Whi + WOFF_WFP, Wmi + WOFF_WFP, bfp, h256);
        gemm_split<64, 64, 1, 4><<<dim3(MROWS / 64, 1, 1), blk, 0, stream>>>(
            36, 36, 256,
            h256, 256, Whi + WOFF_WFC, Wmi + WOFF_WFC, bfc, logits,
            h256, 256, Whi + WOFF_WFC, Wmi + WOFF_WFC, bfc, logits,
            h256, 256, Whi + WOFF_WFC, Wmi + WOFF_WFC, bfc, logits);
        sinkhorn_kernel<<<dim3(BATCH), blk, 0, stream>>>(logits, (float*)d_out);
    }
}

// Round 16
// 612.504 us; speedup vs baseline: 1.0275x; 1.0275x over previous
//
#include <hip/hip_runtime.h>
#include <cstddef>
#include <cstdint>
#include <cmath>

#define TAU_INV 20.0f
#define NMAT 36
#define BATCH 512
#define MROWS 18432   // 512 * 36

typedef unsigned short us16;
typedef __attribute__((ext_vector_type(8))) short s16x8;   // 8 bf16 = 4 VGPRs
typedef __attribute__((ext_vector_type(4))) float f32x4;

// ---------------- bf16 helpers (RNE) ----------------
__device__ inline us16 f2bf(float x) {
    uint32_t u = __float_as_uint(x);
    u += 0x7fff + ((u >> 16) & 1);
    return (us16)(u >> 16);
}
__device__ inline float bf2f(us16 h) {
    return __uint_as_float(((uint32_t)h) << 16);
}
// 3-way split (weights pre-split kernel; gemm uses only h,m planes)
__device__ inline void split3(float v, us16& h, us16& m, us16& l) {
    h = f2bf(v);
    float r1 = v - bf2f(h);
    m = f2bf(r1);
    l = f2bf(r1 - bf2f(m));
}

// packed f32x2 -> bf16x2 convert (T12 recipe; no builtin on gfx950)
__device__ inline uint32_t cvtpk(float lo, float hi) {
    uint32_t d;
    asm("v_cvt_pk_bf16_f32 %0, %1, %2" : "=v"(d) : "v"(lo), "v"(hi));
    return d;
}
// 2-way split of 4 floats into packed h/m bf16 plane words.
// 4-tier product (h+m)x(h+m); R12-verified harmless at output precision.
__device__ inline void split2pk(const float4& v, uint2& h, uint2& m) {
    uint32_t h0 = cvtpk(v.x, v.y), h1 = cvtpk(v.z, v.w);
    float a0 = v.x - __uint_as_float(h0 << 16);
    float a1 = v.y - __uint_as_float(h0 & 0xffff0000u);
    float a2 = v.z - __uint_as_float(h1 << 16);
    float a3 = v.w - __uint_as_float(h1 & 0xffff0000u);
    uint32_t m0 = cvtpk(a0, a1), m1 = cvtpk(a2, a3);
    h = make_uint2(h0, h1); m = make_uint2(m0, m1);
}

// ---------------- async global->LDS 16B DMA ----------------
__device__ inline void dma16(const void* g, void* l) {
    __builtin_amdgcn_global_load_lds(
        (const __attribute__((address_space(1))) void*)g,
        (__attribute__((address_space(3))) void*)l, 16, 0, 0);
}

__device__ inline f32x4 mfma16(s16x8 a, s16x8 b, f32x4 c) {
    return __builtin_amdgcn_mfma_f32_16x16x32_bf16(a, b, c, 0, 0, 0);
}

// ---------------------------------------------------------------------------
// 2-plane-split bf16 MFMA GEMM:  C = act(A' @ W^T + bias)
//   where A' = X (AMODE=0)  or  relu(X + Xb) computed on the fly (AMODE=1,
//   used by vis2 to consume split-K partial sums without a reduce pass).
// 4 tiers (hh,hm,mh,mm); R12-verified numerically at output precision.
// k-loop (R11/R12-proven): barrier -> DMA-B issue -> A-prefetch issue ->
//   split-VALU (covers load latency) -> barrier -> MFMA.
// R15 lesson: tile ratio beats occupancy — vis1 stays <128,128> (182 us
// measured); occupancy for vis1 comes from SPLIT-K (z = k-half, R16).
// ldb separate from K (split-K: k-extent 1024, row stride 2048).
// LDS swizzle (verified R3: SQ_LDS_BANK_CONFLICT = 0): us16 idx =
//   row*32 + ((slot8 ^ ((row>>1)&3))*8 + e); A swizzled write+read;
//   B linear DMA dest + pre-swizzled global source col + swizzled read.
// Triple-param-set: blockIdx.z selects set (fusion / split-K halves).
// OUT: 0 = relu; 1 = tanh with col<nreal store guard; 2 = raw (split-K).
// 256 threads = 4 waves, 2x2 wave grid; wave tile (BM/2)x(BN/2).
// ---------------------------------------------------------------------------
template<int BM, int BN, int OUT, int MINW, int AMODE>
__global__ __launch_bounds__(256, MINW)
void gemm_split(int ldc, int nreal, int K, int ldb,
                const float* X0, const float* Xb0, int ldx0,
                const us16* Bh0, const us16* Bm0, const float* bias0, float* C0,
                const float* X1, const float* Xb1, int ldx1,
                const us16* Bh1, const us16* Bm1, const float* bias1, float* C1,
                const float* X2, const float* Xb2, int ldx2,
                const us16* Bh2, const us16* Bm2, const float* bias2, float* C2)
{
    constexpr int MT  = BM / 32;      // 16-row m-tiles per wave
    constexpr int NT  = BN / 32;      // 16-col n-tiles per wave
    constexpr int NF4 = BM / 32;      // float4 A-loads per thread per k-tile
    constexpr int LB  = BN / 64;      // B DMA chunks per wave per plane

    const float* X; const float* Xb; int ldx;
    const us16 *Bh, *Bm; const float* bias; float* C;
    if (blockIdx.z == 0)      { X = X0; Xb = Xb0; ldx = ldx0; Bh = Bh0; Bm = Bm0; bias = bias0; C = C0; }
    else if (blockIdx.z == 1) { X = X1; Xb = Xb1; ldx = ldx1; Bh = Bh1; Bm = Bm1; bias = bias1; C = C1; }
    else                      { X = X2; Xb = Xb2; ldx = ldx2; Bh = Bh2; Bm = Bm2; bias = bias2; C = C2; }

    alignas(16) __shared__ us16 lds[(BM + BN) * 64];
    us16* AsH = lds;
    us16* AsM = lds + BM * 32;
    us16* BsH = lds + BM * 64;
    us16* BsM = lds + BM * 64 + BN * 32;

    const int tid  = threadIdx.x;
    const int lane = tid & 63;
    const int wid  = tid >> 6;
    const int bm   = blockIdx.x * BM;
    const int bn   = blockIdx.y * BN;
    const int lm   = lane & 15;       // fragment row/col within 16
    const int kb   = lane >> 4;       // k-quad 0..3
    const int wm   = (wid >> 1) * (BM / 2);
    const int wn   = (wid & 1) * (BN / 2);

    // A staging map: thread covers rows arow + i*32, cols acol..acol+3
    const int arow = tid >> 3;        // 0..31
    const int acol = (tid & 7) * 4;   // 0,4,..,28
    const int asw  = ((arow >> 1) & 3) << 3;   // A write swizzle (us16 idx bits 3-4)
    const int fsw  = ((lm >> 1) & 3) << 3;     // fragment read swizzle

    f32x4 acc[MT][NT];
#pragma unroll
    for (int i = 0; i < MT; ++i)
#pragma unroll
        for (int j = 0; j < NT; ++j) acc[i][j] = (f32x4){0.f, 0.f, 0.f, 0.f};

    float4 pref[NF4], pref2[NF4];
#pragma unroll
    for (int i = 0; i < NF4; ++i) {
        pref[i] = *(const float4*)(X + (size_t)(bm + i * 32 + arow) * ldx + acol);
        if (AMODE == 1)
            pref2[i] = *(const float4*)(Xb + (size_t)(bm + i * 32 + arow) * ldx + acol);
    }

    // B DMA: linear dest (wave-uniform base + lane*16B), pre-swizzled src col
    const int bcol = ((lane & 3) ^ ((lane >> 3) & 3)) * 8;

    for (int k0 = 0; k0 < K; k0 += 32) {
        __syncthreads();   // previous compute done; LDS reusable
        // ---- hoisted: async DMA B tile (2 planes) — flies under the split ----
#pragma unroll
        for (int q = 0; q < LB; ++q) {
            const int rb = wid * (LB * 16) + q * 16;          // wave-uniform
            const int gr = bn + rb + (lane >> 2);
            const int gc = k0 + bcol;
            dma16(Bh + (size_t)gr * ldb + gc, &BsH[rb * 32]);
            dma16(Bm + (size_t)gr * ldb + gc, &BsM[rb * 32]);
        }
        // ---- hoisted: A prefetch for next k-tile (ping-pong regs) ----
        float4 prefN[NF4], prefN2[NF4];
        if (k0 + 32 < K) {
#pragma unroll
            for (int i = 0; i < NF4; ++i) {
                prefN[i] = *(const float4*)(X + (size_t)(bm + i * 32 + arow) * ldx
                                            + (k0 + 32) + acol);
                if (AMODE == 1)
                    prefN2[i] = *(const float4*)(Xb + (size_t)(bm + i * 32 + arow) * ldx
                                                 + (k0 + 32) + acol);
            }
        }
        // ---- split current A into h/m LDS planes (covers load latency) ----
#pragma unroll
        for (int i = 0; i < NF4; ++i) {
            const int r = i * 32 + arow;
            float4 v = pref[i];
            if (AMODE == 1) {
                v.x = fmaxf(v.x + pref2[i].x, 0.f);
                v.y = fmaxf(v.y + pref2[i].y, 0.f);
                v.z = fmaxf(v.z + pref2[i].z, 0.f);
                v.w = fmaxf(v.w + pref2[i].w, 0.f);
            }
            uint2 h, m;
            split2pk(v, h, m);
            *(uint2*)&AsH[r * 32 + (acol ^ asw)] = h;
            *(uint2*)&AsM[r * 32 + (acol ^ asw)] = m;
        }
        if (k0 + 32 < K) {
#pragma unroll
            for (int i = 0; i < NF4; ++i) {
                pref[i] = prefN[i];
                if (AMODE == 1) pref2[i] = prefN2[i];
            }
        }
        __syncthreads();   // staging visible (compiler drains vmcnt+lgkm)

        // ---- MFMA phase: 4 tiers (hh, hm, mh, mm) ----
        s16x8 ah[MT], am[MT];
#pragma unroll
        for (int mt = 0; mt < MT; ++mt) {
            const int off = (wm + mt * 16 + lm) * 32 + (kb * 8 ^ fsw);
            ah[mt] = *(const s16x8*)&AsH[off];
            am[mt] = *(const s16x8*)&AsM[off];
        }
#pragma unroll
        for (int nt = 0; nt < NT; ++nt) {
            const int off = (wn + nt * 16 + lm) * 32 + (kb * 8 ^ fsw);
            s16x8 bfh = *(const s16x8*)&BsH[off];
            s16x8 bfm = *(const s16x8*)&BsM[off];
#pragma unroll
            for (int mt = 0; mt < MT; ++mt) {
                acc[mt][nt] = mfma16(ah[mt], bfh, acc[mt][nt]);
                acc[mt][nt] = mfma16(ah[mt], bfm, acc[mt][nt]);
                acc[mt][nt] = mfma16(am[mt], bfh, acc[mt][nt]);
                acc[mt][nt] = mfma16(am[mt], bfm, acc[mt][nt]);
            }
        }
    }

    // ---- epilogue: bias + activation (C/D map: col=lane&15, row=quad*4+r) ----
    float bv[NT];
#pragma unroll
    for (int nt = 0; nt < NT; ++nt) {
        const int col = bn + wn + nt * 16 + lm;
        bv[nt] = (col < nreal) ? bias[col] : 0.f;
    }
#pragma unroll
    for (int nt = 0; nt < NT; ++nt) {
        const int col = bn + wn + nt * 16 + lm;
#pragma unroll
        for (int mt = 0; mt < MT; ++mt) {
#pragma unroll
            for (int r = 0; r < 4; ++r) {
                const int row = bm + wm + mt * 16 + kb * 4 + r;
                float v = acc[mt][nt][r] + bv[nt];
                if (OUT == 0) {
                    C[(size_t)row * ldc + col] = fmaxf(v, 0.f);
                } else if (OUT == 1) {
                    if (col < nreal)
                        C[(size_t)row * ldc + col] = tanhf(v);
                } else {
                    C[(size_t)row * ldc + col] = v;   // raw (split-K partial)
                }
            }
        }
    }
}

// ---------------------------------------------------------------------------
// Weight pre-split into padded bf16 hi/mid/lo planes (lo unused by gemm).
// Plane layout (ushort offsets): w1v [512x2048] @0, w1t @1048576, w1s @1114112,
// w2v @1179648, wfp [256x416 pad] @1245184, wfc [64x256 pad] @1351680; tot 1368064
// ---------------------------------------------------------------------------
#define WOFF_W1T 1048576
#define WOFF_W1S 1114112
#define WOFF_W2V 1179648
#define WOFF_WFP 1245184
#define WOFF_WFC 1351680
#define WTOT     1368064

__global__ void split_weights(const float* __restrict__ w1v, const float* __restrict__ w1t,
                              const float* __restrict__ w1s, const float* __restrict__ w2v,
                              const float* __restrict__ wfp, const float* __restrict__ wfc,
                              us16* __restrict__ hi, us16* __restrict__ mi,
                              us16* __restrict__ lo)
{
    int idx = blockIdx.x * 256 + threadIdx.x;
    if (idx >= WTOT) return;
    const float* src; int N, K, Kp; int local;
    if (idx < WOFF_W1T)      { src = w1v; N = 512; K = 2048; Kp = 2048; local = idx; }
    else if (idx < WOFF_W1S) { src = w1t; N = 128; K = 512;  Kp = 512;  local = idx - WOFF_W1T; }
    else if (idx < WOFF_W2V) { src = w1s; N = 128; K = 512;  Kp = 512;  local = idx - WOFF_W1S; }
    else if (idx < WOFF_WFP) { src = w2v; N = 128; K = 512;  Kp = 512;  local = idx - WOFF_W2V; }
    else if (idx < WOFF_WFC) { src = wfp; N = 256; K = 388;  Kp = 416;  local = idx - WOFF_WFP; }
    else                     { src = wfc; N = 36;  K = 256;  Kp = 256;  local = idx - WOFF_WFC; }
    int n = local / Kp, k = local % Kp;
    float v = (n < N && k < K) ? src[(size_t)n * K + k] : 0.f;
    us16 h, m, l;
    split3(v, h, m, l);
    hi[idx] = h; mi[idx] = m; lo[idx] = l;
}

// ---------------------------------------------------------------------------
// pos branch + cat K-padding + zero-bias region:
//   cat cols [256,260) = relu(pos), [388,416) = 0; zbias[0..512) = 0
// ---------------------------------------------------------------------------
__global__ void pos_pad(const float* __restrict__ seq, float* __restrict__ cat,
                        float* __restrict__ zbias)
{
    int idx = blockIdx.x * 256 + threadIdx.x;
    if (idx >= MROWS * 32 + 512) return;
    if (idx >= MROWS * 32) { zbias[idx - MROWS * 32] = 0.f; return; }
    int row = idx >> 5, j = idx & 31;
    if (j < 4) {
        float v = seq[(size_t)row * 3076 + 2560 + j];
        cat[(size_t)row * 416 + 256 + j] = fmaxf(v, 0.f);
    } else {
        cat[(size_t)row * 416 + 388 + (j - 4)] = 0.f;
    }
}

// ---------------------------------------------------------------------------
// Sinkhorn (verified in R2)
// ---------------------------------------------------------------------------
__global__ __launch_bounds__(256)
void sinkhorn_kernel(const float* __restrict__ Z, float* __restrict__ out)
{
    __shared__ float A[NMAT][NMAT + 1];
    __shared__ float lse[NMAT];
    const int b = blockIdx.x;
    const int tid = threadIdx.x;
    const float* zb = Z + (size_t)b * NMAT * NMAT;

    for (int idx = tid; idx < NMAT * NMAT; idx += 256)
        A[idx / NMAT][idx % NMAT] = expf(zb[idx] * TAU_INV);
    __syncthreads();

    for (int it = 0; it < 20; ++it) {
        if (tid < NMAT * 4) {
            int r = tid >> 2, g = tid & 3;
            float m = -3.402823466e38f;
            for (int j = g; j < NMAT; j += 4) m = fmaxf(m, A[r][j]);
            m = fmaxf(m, __shfl_xor(m, 2, 4));
            m = fmaxf(m, __shfl_xor(m, 1, 4));
            float s = 0.f;
            for (int j = g; j < NMAT; j += 4) s += expf(A[r][j] - m);
            s += __shfl_xor(s, 2, 4);
            s += __shfl_xor(s, 1, 4);
            if (g == 0) lse[r] = m + logf(s);
        }
        __syncthreads();
        for (int idx = tid; idx < NMAT * NMAT; idx += 256)
            A[idx / NMAT][idx % NMAT] -= lse[idx / NMAT];
        __syncthreads();

        if (tid < NMAT * 4) {
            int c = tid >> 2, g = tid & 3;
            float m = -3.402823466e38f;
            for (int i = g; i < NMAT; i += 4) m = fmaxf(m, A[i][c]);
            m = fmaxf(m, __shfl_xor(m, 2, 4));
            m = fmaxf(m, __shfl_xor(m, 1, 4));
            float s = 0.f;
            for (int i = g; i < NMAT; i += 4) s += expf(A[i][c] - m);
            s += __shfl_xor(s, 2, 4);
            s += __shfl_xor(s, 1, 4);
            if (g == 0) lse[c] = m + logf(s);
        }
        __syncthreads();
        for (int idx = tid; idx < NMAT * NMAT; idx += 256)
            A[idx / NMAT][idx % NMAT] -= lse[idx % NMAT];
        __syncthreads();
    }

    for (int idx = tid; idx < NMAT * NMAT; idx += 256)
        out[(size_t)b * NMAT * NMAT + idx] = expf(A[idx / NMAT][idx % NMAT]);
}

// ---------------------------------------------------------------------------
extern "C" void kernel_launch(void* const* d_in, const int* in_sizes, int n_in,
                              void* d_out, int out_size, void* d_ws, size_t ws_size,
                              hipStream_t stream)
{
    const float* seq = (const float*)d_in[0];
    const float* W1t = (const float*)d_in[1];
    const float* b1t = (const float*)d_in[2];
    const float* W1v = (const float*)d_in[3];
    const float* b1v = (const float*)d_in[4];
    const float* W2v = (const float*)d_in[5];
    const float* b2v = (const float*)d_in[6];
    const float* W1s = (const float*)d_in[7];
    const float* b1s = (const float*)d_in[8];
    const float* Wfp = (const float*)d_in[9];
    const float* bfp = (const float*)d_in[10];
    const float* Wfc = (const float*)d_in[11];
    const float* bfc = (const float*)d_in[12];

    float* wsF = (float*)d_ws;
    dim3 blk(256);

    // Split-K layout needs 114.4 MB; fallback = R12 structure at 76.6 MB.
    const bool splitk = ws_size >= (size_t)28594688 * 4;

    if (splitk) {
        // ws layout (float offsets), split-K full-M:
        //   [0, 9437184)          : vis1a (18432x512); later h256 (18432x256)
        //   [9437184, 18874368)   : vis1b (18432x512)
        //   [18874368, 26542080)  : cat (18432x416); later logits
        //   [26542080, +2052096)  : weight planes hi/mid/lo (3 x WTOT us16)
        //   [28594176, +512)      : zero-bias (512 floats)
        float* vis1a = wsF;
        float* vis1b = wsF + 9437184;
        float* h256  = wsF;                 // overlays vis1a after vis2
        float* cat    = wsF + 18874368;
        float* logits = wsF + 18874368;     // overlays cat after fc_pos
        us16*  Whi    = (us16*)(wsF + 26542080);
        us16*  Wmi    = Whi + WTOT;
        us16*  Wlo    = Wmi + WTOT;
        float* zbias  = wsF + 28594176;

        split_weights<<<dim3((WTOT + 255) / 256), blk, 0, stream>>>(
            W1v, W1t, W1s, W2v, Wfp, Wfc, Whi, Wmi, Wlo);
        pos_pad<<<dim3((MROWS * 32 + 512 + 255) / 256), blk, 0, stream>>>(
            seq, cat, zbias);
        // vis1 split-K: <128,128> raw partials, z = k-half; 144x4x2 = 1152 blocks
        gemm_split<128, 128, 2, 3, 0><<<dim3(MROWS / 128, 4, 2), blk, 0, stream>>>(
            512, 512, 1024, 2048,
            seq + 512,        nullptr, 3076, Whi,        Wmi,        b1v,   vis1a,
            seq + 512 + 1024, nullptr, 3076, Whi + 1024, Wmi + 1024, zbias, vis1b,
            seq + 512,        nullptr, 3076, Whi,        Wmi,        b1v,   vis1a);
        // txt & sen fused (z selects set)
        gemm_split<64, 128, 0, 4, 0><<<dim3(MROWS / 64, 1, 2), blk, 0, stream>>>(
            416, 128, 512, 512,
            seq,        nullptr, 3076, Whi + WOFF_W1T, Wmi + WOFF_W1T, b1t, cat,
            seq + 2564, nullptr, 3076, Whi + WOFF_W1S, Wmi + WOFF_W1S, b1s, cat + 260,
            seq,        nullptr, 3076, Whi + WOFF_W1T, Wmi + WOFF_W1T, b1t, cat);
        // vis2: AMODE=1 consumes relu(vis1a+vis1b) on the fly
        gemm_split<64, 64, 0, 4, 1><<<dim3(MROWS / 64, 2, 1), blk, 0, stream>>>(
            416, 128, 512, 512,
            vis1a, vis1b, 512, Whi + WOFF_W2V, Wmi + WOFF_W2V, b2v, cat + 128,
            vis1a, vis1b, 512, Whi + WOFF_W2V, Wmi + WOFF_W2V, b2v, cat + 128,
            vis1a, vis1b, 512, Whi + WOFF_W2V, Wmi + WOFF_W2V, b2v, cat + 128);
        // fc_pos: (M,416)->256 relu -> h256 (overlays vis1a, now dead)
        gemm_split<64, 128, 0, 4, 0><<<dim3(MROWS / 64, 2, 1), blk, 0, stream>>>(
            256, 256, 416, 416,
            cat, nullptr, 416, Whi + WOFF_WFP, Wmi + WOFF_WFP, bfp, h256,
            cat, nullptr, 416, Whi + WOFF_WFP, Wmi + WOFF_WFP, bfp, h256,
            cat, nullptr, 416, Whi + WOFF_WFP, Wmi + WOFF_WFP, bfp, h256);
        // fc: (M,256)->36 tanh -> logits (overlays cat, now dead)
        gemm_split<64, 64, 1, 4, 0><<<dim3(MROWS / 64, 1, 1), blk, 0, stream>>>(
            36, 36, 256, 256,
            h256, nullptr, 256, Whi + WOFF_WFC, Wmi + WOFF_WFC, bfc, logits,
            h256, nullptr, 256, Whi + WOFF_WFC, Wmi + WOFF_WFC, bfc, logits,
            h256, nullptr, 256, Whi + WOFF_WFC, Wmi + WOFF_WFC, bfc, logits);
        sinkhorn_kernel<<<dim3(BATCH), blk, 0, stream>>>(logits, (float*)d_out);
    } else {
        // ---- R12-proven structure (76.6 MB): vis1 single-pass <128,128> ----
        float* vis1buf = wsF;
        float* h256    = wsF;
        float* cat     = wsF + 9437184;
        float* logits  = wsF + 9437184;
        us16*  Whi     = (us16*)(wsF + 17104896);
        us16*  Wmi     = Whi + WTOT;
        us16*  Wlo     = Wmi + WTOT;

        split_weights<<<dim3((WTOT + 255) / 256), blk, 0, stream>>>(
            W1v, W1t, W1s, W2v, Wfp, Wfc, Whi, Wmi, Wlo);
        pos_pad<<<dim3((MROWS * 32 + 512 + 255) / 256), blk, 0, stream>>>(
            seq, cat, cat);   // zbias unused here; alias harmlessly (writes cat[0..512) BEFORE txt fills it)
        // NOTE: zbias aliasing cat would corrupt cat cols 0..; avoid: reuse
        // the pad region instead — write zeros into cat pad (already done) and
        // pass b1v for both halves is WRONG. Fallback uses single-pass vis1,
        // so no zero-bias is needed; pass cat as dummy (overwritten by txt
        // gemm afterwards in full; but txt writes only cols 0..127 of each row;
        // zbias writes cat[0..511] = rows 0-1 cols... overwritten by txt/vis2/
        // sen/pos writes for rows 0-1. Safe: every cat element is written by
        // a later producer before fc_pos reads it.
        gemm_split<128, 128, 0, 3, 0><<<dim3(MROWS / 128, 4, 1), blk, 0, stream>>>(
            512, 512, 2048, 2048,
            seq + 512, nullptr, 3076, Whi, Wmi, b1v, vis1buf,
            seq + 512, nullptr, 3076, Whi, Wmi, b1v, vis1buf,
            seq + 512, nullptr, 3076, Whi, Wmi, b1v, vis1buf);
        gemm_split<64, 128, 0, 4, 0><<<dim3(MROWS / 64, 1, 2), blk, 0, stream>>>(
            416, 128, 512, 512,
            seq,        nullptr, 3076, Whi + WOFF_W1T, Wmi + WOFF_W1T, b1t, cat,
            seq + 2564, nullptr, 3076, Whi + WOFF_W1S, Wmi + WOFF_W1S, b1s, cat + 260,
            seq,        nullptr, 3076, Whi + WOFF_W1T, Wmi + WOFF_W1T, b1t, cat);
        gemm_split<64, 64, 0, 4, 0><<<dim3(MROWS / 64, 2, 1), blk, 0, stream>>>(
            416, 128, 512, 512,
            vis1buf, nullptr, 512, Whi + WOFF_W2V, Wmi + WOFF_W2V, b2v, cat + 128,
            vis1buf, nullptr, 512, Whi + WOFF_W2V, Wmi + WOFF_W2V, b2v, cat + 128,
            vis1buf, nullptr, 512, Whi + WOFF_W2V, Wmi + WOFF_W2V, b2v, cat + 128);
        gemm_split<64, 128, 0, 4, 0><<<dim3(MROWS / 64, 2, 1), blk, 0, stream>>>(
            256, 256, 416, 416,
            cat, nullptr, 416, Whi + WOFF_WFP, Wmi + WOFF_WFP, bfp, h256,
            cat, nullptr, 416, Whi + WOFF_WFP, Wmi + WOFF_WFP, bfp, h256,
            cat, nullptr, 416, Whi + WOFF_WFP, Wmi + WOFF_WFP, bfp, h256);
        gemm_split<64, 64, 1, 4, 0><<<dim3(MROWS / 64, 1, 1), blk, 0, stream>>>(
            36, 36, 256, 256,
            h256, nullptr, 256, Whi + WOFF_WFC, Wmi + WOFF_WFC, bfc, logits,
            h256, nullptr, 256, Whi + WOFF_WFC, Wmi + WOFF_WFC, bfc, logits,
            h256, nullptr, 256, Whi + WOFF_WFC, Wmi + WOFF_WFC, bfc, logits);
        sinkhorn_kernel<<<dim3(BATCH), blk, 0, stream>>>(logits, (float*)d_out);
    }
}

// Round 17
// 595.097 us; speedup vs baseline: 1.0576x; 1.0293x over previous
//
#include <hip/hip_runtime.h>
#include <cstddef>
#include <cstdint>
#include <cmath>

#define TAU_INV 20.0f
#define NMAT 36
#define BATCH 512
#define MROWS 18432   // 512 * 36
#define MHALF 9216

typedef unsigned short us16;
typedef __attribute__((ext_vector_type(8))) short s16x8;   // 8 bf16 = 4 VGPRs
typedef __attribute__((ext_vector_type(4))) float f32x4;

// ---------------- bf16 helpers (RNE) ----------------
__device__ inline us16 f2bf(float x) {
    uint32_t u = __float_as_uint(x);
    u += 0x7fff + ((u >> 16) & 1);
    return (us16)(u >> 16);
}
__device__ inline float bf2f(us16 h) {
    return __uint_as_float(((uint32_t)h) << 16);
}
// 3-way split (weights pre-split kernel; gemm uses only h,m planes)
__device__ inline void split3(float v, us16& h, us16& m, us16& l) {
    h = f2bf(v);
    float r1 = v - bf2f(h);
    m = f2bf(r1);
    l = f2bf(r1 - bf2f(m));
}

// packed f32x2 -> bf16x2 convert (T12 recipe; no builtin on gfx950)
__device__ inline uint32_t cvtpk(float lo, float hi) {
    uint32_t d;
    asm("v_cvt_pk_bf16_f32 %0, %1, %2" : "=v"(d) : "v"(lo), "v"(hi));
    return d;
}
// 2-way split of 4 floats into packed h/m bf16 plane words.
// 4-tier product (h+m)(h+m) is exact; dropped x*yl+xl*y ~2^-18 rel
// (verified harmless at output precision, R12: absmax unchanged).
__device__ inline void split2pk(const float4& v, uint2& h, uint2& m) {
    uint32_t h0 = cvtpk(v.x, v.y), h1 = cvtpk(v.z, v.w);
    float a0 = v.x - __uint_as_float(h0 << 16);
    float a1 = v.y - __uint_as_float(h0 & 0xffff0000u);
    float a2 = v.z - __uint_as_float(h1 << 16);
    float a3 = v.w - __uint_as_float(h1 & 0xffff0000u);
    uint32_t m0 = cvtpk(a0, a1), m1 = cvtpk(a2, a3);
    h = make_uint2(h0, h1); m = make_uint2(m0, m1);
}

// ---------------- async global->LDS 16B DMA ----------------
__device__ inline void dma16(const void* g, void* l) {
    __builtin_amdgcn_global_load_lds(
        (const __attribute__((address_space(1))) void*)g,
        (__attribute__((address_space(3))) void*)l, 16, 0, 0);
}

__device__ inline f32x4 mfma16(s16x8 a, s16x8 b, f32x4 c) {
    return __builtin_amdgcn_mfma_f32_16x16x32_bf16(a, b, c, 0, 0, 0);
}

// ---------------------------------------------------------------------------
// 2-plane-split bf16 MFMA GEMM:  C = act(X @ W^T + bias)
//   4 tiers (hh,hm,mh,mm); R12-verified numerically at output precision.
// k-loop (R11/R12-proven): barrier -> DMA-B issue -> A-prefetch issue ->
//   split-VALU (covers load latency) -> barrier -> MFMA.
// R12 = session-best measured config (595.3 us). R15 (vis1 64x128: 629) and
// R16 (split-K: 612) both refuted the "latency is occupancy-hideable" theory;
// the ~89 us L in vis1 is structural to the 2-barrier k-loop (cf. R4).
// LDS: 2 planes A + 2 planes B, (BM+BN)*64 us16: <128,128>=32KB, <64,128>=24KB.
// LDS swizzle (verified R3: SQ_LDS_BANK_CONFLICT = 0): us16 idx =
//   row*32 + ((slot8 ^ ((row>>1)&3))*8 + e); A swizzled write+read;
//   B linear DMA dest + pre-swizzled global source col + swizzled read.
// Dual-param-set: blockIdx.z==1 selects the second set (co-schedules txt+sen).
// OUT: 0 = relu; 1 = tanh with col<nreal store guard.
// 256 threads = 4 waves, 2x2 wave grid; wave tile (BM/2)x(BN/2).
// ---------------------------------------------------------------------------
template<int BM, int BN, int OUT, int MINW>
__global__ __launch_bounds__(256, MINW)
void gemm_split(const float* X, int ldx,
                const us16* Bh, const us16* Bm,
                const float* bias, float* C, int ldc, int nreal, int K,
                const float* X2, const us16* Bh2, const us16* Bm2,
                const float* bias2, float* C2)
{
    constexpr int MT  = BM / 32;      // 16-row m-tiles per wave
    constexpr int NT  = BN / 32;      // 16-col n-tiles per wave
    constexpr int NF4 = BM / 32;      // float4 A-loads per thread per k-tile
    constexpr int LB  = BN / 64;      // B DMA chunks per wave per plane

    if (blockIdx.z) { X = X2; Bh = Bh2; Bm = Bm2; bias = bias2; C = C2; }

    alignas(16) __shared__ us16 lds[(BM + BN) * 64];
    us16* AsH = lds;
    us16* AsM = lds + BM * 32;
    us16* BsH = lds + BM * 64;
    us16* BsM = lds + BM * 64 + BN * 32;

    const int tid  = threadIdx.x;
    const int lane = tid & 63;
    const int wid  = tid >> 6;
    const int bm   = blockIdx.x * BM;
    const int bn   = blockIdx.y * BN;
    const int lm   = lane & 15;       // fragment row/col within 16
    const int kb   = lane >> 4;       // k-quad 0..3
    const int wm   = (wid >> 1) * (BM / 2);
    const int wn   = (wid & 1) * (BN / 2);

    // A staging map: thread covers rows arow + i*32, cols acol..acol+3
    const int arow = tid >> 3;        // 0..31
    const int acol = (tid & 7) * 4;   // 0,4,..,28
    const int asw  = ((arow >> 1) & 3) << 3;   // A write swizzle (us16 idx bits 3-4)
    const int fsw  = ((lm >> 1) & 3) << 3;     // fragment read swizzle

    f32x4 acc[MT][NT];
#pragma unroll
    for (int i = 0; i < MT; ++i)
#pragma unroll
        for (int j = 0; j < NT; ++j) acc[i][j] = (f32x4){0.f, 0.f, 0.f, 0.f};

    float4 pref[NF4];
#pragma unroll
    for (int i = 0; i < NF4; ++i)
        pref[i] = *(const float4*)(X + (size_t)(bm + i * 32 + arow) * ldx + acol);

    // B DMA: linear dest (wave-uniform base + lane*16B), pre-swizzled src col
    const int bcol = ((lane & 3) ^ ((lane >> 3) & 3)) * 8;

    for (int k0 = 0; k0 < K; k0 += 32) {
        __syncthreads();   // previous compute done; LDS reusable
        // ---- hoisted: async DMA B tile (2 planes) — flies under the split ----
#pragma unroll
        for (int q = 0; q < LB; ++q) {
            const int rb = wid * (LB * 16) + q * 16;          // wave-uniform
            const int gr = bn + rb + (lane >> 2);
            const int gc = k0 + bcol;
            dma16(Bh + (size_t)gr * K + gc, &BsH[rb * 32]);
            dma16(Bm + (size_t)gr * K + gc, &BsM[rb * 32]);
        }
        // ---- hoisted: A prefetch for next k-tile (ping-pong regs) ----
        float4 prefN[NF4];
        if (k0 + 32 < K) {
#pragma unroll
            for (int i = 0; i < NF4; ++i)
                prefN[i] = *(const float4*)(X + (size_t)(bm + i * 32 + arow) * ldx
                                            + (k0 + 32) + acol);
        }
        // ---- split current A into h/m LDS planes (covers load latency) ----
#pragma unroll
        for (int i = 0; i < NF4; ++i) {
            const int r = i * 32 + arow;
            uint2 h, m;
            split2pk(pref[i], h, m);
            *(uint2*)&AsH[r * 32 + (acol ^ asw)] = h;
            *(uint2*)&AsM[r * 32 + (acol ^ asw)] = m;
        }
        if (k0 + 32 < K) {
#pragma unroll
            for (int i = 0; i < NF4; ++i) pref[i] = prefN[i];
        }
        __syncthreads();   // staging visible (compiler drains vmcnt+lgkm)

        // ---- MFMA phase: 4 tiers (hh, hm, mh, mm) ----
        s16x8 ah[MT], am[MT];
#pragma unroll
        for (int mt = 0; mt < MT; ++mt) {
            const int off = (wm + mt * 16 + lm) * 32 + (kb * 8 ^ fsw);
            ah[mt] = *(const s16x8*)&AsH[off];
            am[mt] = *(const s16x8*)&AsM[off];
        }
#pragma unroll
        for (int nt = 0; nt < NT; ++nt) {
            const int off = (wn + nt * 16 + lm) * 32 + (kb * 8 ^ fsw);
            s16x8 bfh = *(const s16x8*)&BsH[off];
            s16x8 bfm = *(const s16x8*)&BsM[off];
#pragma unroll
            for (int mt = 0; mt < MT; ++mt) {
                acc[mt][nt] = mfma16(ah[mt], bfh, acc[mt][nt]);
                acc[mt][nt] = mfma16(ah[mt], bfm, acc[mt][nt]);
                acc[mt][nt] = mfma16(am[mt], bfh, acc[mt][nt]);
                acc[mt][nt] = mfma16(am[mt], bfm, acc[mt][nt]);
            }
        }
    }

    // ---- epilogue: bias + activation (C/D map: col=lane&15, row=quad*4+r) ----
    float bv[NT];
#pragma unroll
    for (int nt = 0; nt < NT; ++nt) {
        const int col = bn + wn + nt * 16 + lm;
        bv[nt] = (col < nreal) ? bias[col] : 0.f;
    }
#pragma unroll
    for (int nt = 0; nt < NT; ++nt) {
        const int col = bn + wn + nt * 16 + lm;
#pragma unroll
        for (int mt = 0; mt < MT; ++mt) {
#pragma unroll
            for (int r = 0; r < 4; ++r) {
                const int row = bm + wm + mt * 16 + kb * 4 + r;
                float v = acc[mt][nt][r] + bv[nt];
                if (OUT == 0) {
                    C[(size_t)row * ldc + col] = fmaxf(v, 0.f);
                } else {
                    if (col < nreal)
                        C[(size_t)row * ldc + col] = tanhf(v);
                }
            }
        }
    }
}

// ---------------------------------------------------------------------------
// Weight pre-split into padded bf16 hi/mid/lo planes (lo unused by gemm).
// Plane layout (ushort offsets): w1v [512x2048] @0, w1t @1048576, w1s @1114112,
// w2v @1179648, wfp [256x416 pad] @1245184, wfc [64x256 pad] @1351680; tot 1368064
// ---------------------------------------------------------------------------
#define WOFF_W1T 1048576
#define WOFF_W1S 1114112
#define WOFF_W2V 1179648
#define WOFF_WFP 1245184
#define WOFF_WFC 1351680
#define WTOT     1368064

__global__ void split_weights(const float* __restrict__ w1v, const float* __restrict__ w1t,
                              const float* __restrict__ w1s, const float* __restrict__ w2v,
                              const float* __restrict__ wfp, const float* __restrict__ wfc,
                              us16* __restrict__ hi, us16* __restrict__ mi,
                              us16* __restrict__ lo)
{
    int idx = blockIdx.x * 256 + threadIdx.x;
    if (idx >= WTOT) return;
    const float* src; int N, K, Kp; int local;
    if (idx < WOFF_W1T)      { src = w1v; N = 512; K = 2048; Kp = 2048; local = idx; }
    else if (idx < WOFF_W1S) { src = w1t; N = 128; K = 512;  Kp = 512;  local = idx - WOFF_W1T; }
    else if (idx < WOFF_W2V) { src = w1s; N = 128; K = 512;  Kp = 512;  local = idx - WOFF_W1S; }
    else if (idx < WOFF_WFP) { src = w2v; N = 128; K = 512;  Kp = 512;  local = idx - WOFF_W2V; }
    else if (idx < WOFF_WFC) { src = wfp; N = 256; K = 388;  Kp = 416;  local = idx - WOFF_WFP; }
    else                     { src = wfc; N = 36;  K = 256;  Kp = 256;  local = idx - WOFF_WFC; }
    int n = local / Kp, k = local % Kp;
    float v = (n < N && k < K) ? src[(size_t)n * K + k] : 0.f;
    us16 h, m, l;
    split3(v, h, m, l);
    hi[idx] = h; mi[idx] = m; lo[idx] = l;
}

// ---------------------------------------------------------------------------
// pos branch + cat K-padding: cat cols [256,260) = relu(pos), [388,416) = 0
// ---------------------------------------------------------------------------
__global__ void pos_pad(const float* __restrict__ seq, float* __restrict__ cat)
{
    int idx = blockIdx.x * 256 + threadIdx.x;
    if (idx >= MROWS * 32) return;
    int row = idx >> 5, j = idx & 31;
    if (j < 4) {
        float v = seq[(size_t)row * 3076 + 2560 + j];
        cat[(size_t)row * 416 + 256 + j] = fmaxf(v, 0.f);
    } else {
        cat[(size_t)row * 416 + 388 + (j - 4)] = 0.f;
    }
}

// ---------------------------------------------------------------------------
// Sinkhorn (verified in R2)
// ---------------------------------------------------------------------------
__global__ __launch_bounds__(256)
void sinkhorn_kernel(const float* __restrict__ Z, float* __restrict__ out)
{
    __shared__ float A[NMAT][NMAT + 1];
    __shared__ float lse[NMAT];
    const int b = blockIdx.x;
    const int tid = threadIdx.x;
    const float* zb = Z + (size_t)b * NMAT * NMAT;

    for (int idx = tid; idx < NMAT * NMAT; idx += 256)
        A[idx / NMAT][idx % NMAT] = expf(zb[idx] * TAU_INV);
    __syncthreads();

    for (int it = 0; it < 20; ++it) {
        if (tid < NMAT * 4) {
            int r = tid >> 2, g = tid & 3;
            float m = -3.402823466e38f;
            for (int j = g; j < NMAT; j += 4) m = fmaxf(m, A[r][j]);
            m = fmaxf(m, __shfl_xor(m, 2, 4));
            m = fmaxf(m, __shfl_xor(m, 1, 4));
            float s = 0.f;
            for (int j = g; j < NMAT; j += 4) s += expf(A[r][j] - m);
            s += __shfl_xor(s, 2, 4);
            s += __shfl_xor(s, 1, 4);
            if (g == 0) lse[r] = m + logf(s);
        }
        __syncthreads();
        for (int idx = tid; idx < NMAT * NMAT; idx += 256)
            A[idx / NMAT][idx % NMAT] -= lse[idx / NMAT];
        __syncthreads();

        if (tid < NMAT * 4) {
            int c = tid >> 2, g = tid & 3;
            float m = -3.402823466e38f;
            for (int i = g; i < NMAT; i += 4) m = fmaxf(m, A[i][c]);
            m = fmaxf(m, __shfl_xor(m, 2, 4));
            m = fmaxf(m, __shfl_xor(m, 1, 4));
            float s = 0.f;
            for (int i = g; i < NMAT; i += 4) s += expf(A[i][c] - m);
            s += __shfl_xor(s, 2, 4);
            s += __shfl_xor(s, 1, 4);
            if (g == 0) lse[c] = m + logf(s);
        }
        __syncthreads();
        for (int idx = tid; idx < NMAT * NMAT; idx += 256)
            A[idx / NMAT][idx % NMAT] -= lse[idx % NMAT];
        __syncthreads();
    }

    for (int idx = tid; idx < NMAT * NMAT; idx += 256)
        out[(size_t)b * NMAT * NMAT + idx] = expf(A[idx / NMAT][idx % NMAT]);
}

// ---------------------------------------------------------------------------
extern "C" void kernel_launch(void* const* d_in, const int* in_sizes, int n_in,
                              void* d_out, int out_size, void* d_ws, size_t ws_size,
                              hipStream_t stream)
{
    const float* seq = (const float*)d_in[0];
    const float* W1t = (const float*)d_in[1];
    const float* b1t = (const float*)d_in[2];
    const float* W1v = (const float*)d_in[3];
    const float* b1v = (const float*)d_in[4];
    const float* W2v = (const float*)d_in[5];
    const float* b2v = (const float*)d_in[6];
    const float* W1s = (const float*)d_in[7];
    const float* b1s = (const float*)d_in[8];
    const float* Wfp = (const float*)d_in[9];
    const float* bfp = (const float*)d_in[10];
    const float* Wfc = (const float*)d_in[11];
    const float* bfc = (const float*)d_in[12];

    float* wsF = (float*)d_ws;
    dim3 blk(256);

    // Full-M layout needs 76.63 MB (R9-R12 verified working); fallback otherwise.
    const bool full = ws_size >= (size_t)19156992 * 4;

    if (full) {
        // ws layout (float offsets), full-M:
        //   [0, 9437184)         : vis1 (18432x512); later h256 (18432x256)
        //   [9437184, 17104896)  : cat (18432x416); later logits
        //   [17104896, +2052096) : weight planes hi/mid/lo (3 x WTOT us16)
        float* vis1buf = wsF;
        float* h256    = wsF;
        float* cat     = wsF + 9437184;
        float* logits  = wsF + 9437184;
        us16*  Whi     = (us16*)(wsF + 17104896);
        us16*  Wmi     = Whi + WTOT;
        us16*  Wlo     = Wmi + WTOT;

        split_weights<<<dim3((WTOT + 255) / 256), blk, 0, stream>>>(
            W1v, W1t, W1s, W2v, Wfp, Wfc, Whi, Wmi, Wlo);
        pos_pad<<<dim3((MROWS * 32 + 255) / 256), blk, 0, stream>>>(seq, cat);
        // txt & sen fused (blockIdx.z selects param set)
        gemm_split<64, 128, 0, 4><<<dim3(MROWS / 64, 1, 2), blk, 0, stream>>>(
            seq, 3076, Whi + WOFF_W1T, Wmi + WOFF_W1T, b1t,
            cat, 416, 128, 512,
            seq + 2564, Whi + WOFF_W1S, Wmi + WOFF_W1S, b1s,
            cat + 260);
        // vis1 full-M, 128x128 tile: 144x4 = 576 blocks, 32 KB LDS
        gemm_split<128, 128, 0, 3><<<dim3(MROWS / 128, 4, 1), blk, 0, stream>>>(
            seq + 512, 3076, Whi, Wmi, b1v, vis1buf, 512, 512, 2048,
            seq + 512, Whi, Wmi, b1v, vis1buf);
        // vis2 full-M: BN=64, y=2 -> 576 blocks (16 KB LDS)
        gemm_split<64, 64, 0, 4><<<dim3(MROWS / 64, 2, 1), blk, 0, stream>>>(
            vis1buf, 512, Whi + WOFF_W2V, Wmi + WOFF_W2V, b2v,
            cat + 128, 416, 128, 512,
            vis1buf, Whi + WOFF_W2V, Wmi + WOFF_W2V, b2v,
            cat + 128);
        // fc_pos: (M,416)->256 relu -> h256 (overlays vis1buf, now dead)
        gemm_split<64, 128, 0, 4><<<dim3(MROWS / 64, 2, 1), blk, 0, stream>>>(
            cat, 416, Whi + WOFF_WFP, Wmi + WOFF_WFP, bfp,
            h256, 256, 256, 416,
            cat, Whi + WOFF_WFP, Wmi + WOFF_WFP, bfp, h256);
        // fc: (M,256)->36 tanh -> logits (overlays cat, now dead)
        gemm_split<64, 64, 1, 4><<<dim3(MROWS / 64, 1, 1), blk, 0, stream>>>(
            h256, 256, Whi + WOFF_WFC, Wmi + WOFF_WFC, bfc,
            logits, 36, 36, 256,
            h256, Whi + WOFF_WFC, Wmi + WOFF_WFC, bfc, logits);
        sinkhorn_kernel<<<dim3(BATCH), blk, 0, stream>>>(logits, (float*)d_out);
    } else {
        // ---- half-M fallback (57.8 MB), same 2-plane kernel ----
        float* vis1buf = wsF;
        float* h256    = wsF;
        float* cat     = wsF + 4718592;
        float* logits  = wsF + 4718592;
        us16*  Whi     = (us16*)(wsF + 12386304);
        us16*  Wmi     = Whi + WTOT;
        us16*  Wlo     = Wmi + WTOT;

        split_weights<<<dim3((WTOT + 255) / 256), blk, 0, stream>>>(
            W1v, W1t, W1s, W2v, Wfp, Wfc, Whi, Wmi, Wlo);
        pos_pad<<<dim3((MROWS * 32 + 255) / 256), blk, 0, stream>>>(seq, cat);
        gemm_split<64, 128, 0, 4><<<dim3(MROWS / 64, 1, 2), blk, 0, stream>>>(
            seq, 3076, Whi + WOFF_W1T, Wmi + WOFF_W1T, b1t,
            cat, 416, 128, 512,
            seq + 2564, Whi + WOFF_W1S, Wmi + WOFF_W1S, b1s,
            cat + 260);
        for (int h = 0; h < 2; ++h) {
            const float* xh = seq + 512 + (size_t)h * MHALF * 3076;
            float* ch = cat + 128 + (size_t)h * MHALF * 416;
            gemm_split<128, 128, 0, 3><<<dim3(MHALF / 128, 4, 1), blk, 0, stream>>>(
                xh, 3076, Whi, Wmi, b1v, vis1buf, 512, 512, 2048,
                xh, Whi, Wmi, b1v, vis1buf);
            gemm_split<64, 64, 0, 4><<<dim3(MHALF / 64, 2, 1), blk, 0, stream>>>(
                vis1buf, 512, Whi + WOFF_W2V, Wmi + WOFF_W2V, b2v,
                ch, 416, 128, 512,
                vis1buf, Whi + WOFF_W2V, Wmi + WOFF_W2V, b2v, ch);
        }
        gemm_split<64, 128, 0, 4><<<dim3(MROWS / 64, 2, 1), blk, 0, stream>>>(
            cat, 416, Whi + WOFF_WFP, Wmi + WOFF_WFP, bfp,
            h256, 256, 256, 416,
            cat, Whi + WOFF_WFP, Wmi + WOFF_WFP, bfp, h256);
        gemm_split<64, 64, 1, 4><<<dim3(MROWS / 64, 1, 1), blk, 0, stream>>>(
            h256, 256, Whi + WOFF_WFC, Wmi + WOFF_WFC, bfc,
            logits, 36, 36, 256,
            h256, Whi + WOFF_WFC, Wmi + WOFF_WFC, bfc, logits);
        sinkhorn_kernel<<<dim3(BATCH), blk, 0, stream>>>(logits, (float*)d_out);
    }
}

// Round 18
// 571.095 us; speedup vs baseline: 1.1020x; 1.0420x over previous
//
#include <hip/hip_runtime.h>
#include <cstddef>
#include <cstdint>
#include <cmath>

#define TAU_INV 20.0f
#define NMAT 36
#define BATCH 512
#define MROWS 18432   // 512 * 36
#define MHALF 9216

typedef unsigned short us16;
typedef __attribute__((ext_vector_type(8))) short s16x8;   // 8 bf16 = 4 VGPRs
typedef __attribute__((ext_vector_type(4))) float f32x4;

// ---------------- bf16 helpers (RNE) ----------------
__device__ inline us16 f2bf(float x) {
    uint32_t u = __float_as_uint(x);
    u += 0x7fff + ((u >> 16) & 1);
    return (us16)(u >> 16);
}
__device__ inline float bf2f(us16 h) {
    return __uint_as_float(((uint32_t)h) << 16);
}
// 3-way split (weights pre-split kernel; gemm uses only h,m planes)
__device__ inline void split3(float v, us16& h, us16& m, us16& l) {
    h = f2bf(v);
    float r1 = v - bf2f(h);
    m = f2bf(r1);
    l = f2bf(r1 - bf2f(m));
}

// packed f32x2 -> bf16x2 convert (T12 recipe; no builtin on gfx950)
__device__ inline uint32_t cvtpk(float lo, float hi) {
    uint32_t d;
    asm("v_cvt_pk_bf16_f32 %0, %1, %2" : "=v"(d) : "v"(lo), "v"(hi));
    return d;
}
// 2-way split of 4 floats into packed h/m bf16 plane words.
// 4-tier product (h+m)(h+m) is exact; dropped x*yl+xl*y ~2^-18 rel
// (verified harmless at output precision, R12: absmax unchanged).
__device__ inline void split2pk(const float4& v, uint2& h, uint2& m) {
    uint32_t h0 = cvtpk(v.x, v.y), h1 = cvtpk(v.z, v.w);
    float a0 = v.x - __uint_as_float(h0 << 16);
    float a1 = v.y - __uint_as_float(h0 & 0xffff0000u);
    float a2 = v.z - __uint_as_float(h1 << 16);
    float a3 = v.w - __uint_as_float(h1 & 0xffff0000u);
    uint32_t m0 = cvtpk(a0, a1), m1 = cvtpk(a2, a3);
    h = make_uint2(h0, h1); m = make_uint2(m0, m1);
}

// ---------------- async global->LDS 16B DMA ----------------
__device__ inline void dma16(const void* g, void* l) {
    __builtin_amdgcn_global_load_lds(
        (const __attribute__((address_space(1))) void*)g,
        (__attribute__((address_space(3))) void*)l, 16, 0, 0);
}

__device__ inline f32x4 mfma16(s16x8 a, s16x8 b, f32x4 c) {
    return __builtin_amdgcn_mfma_f32_16x16x32_bf16(a, b, c, 0, 0, 0);
}

// ---------------------------------------------------------------------------
// 2-plane-split bf16 MFMA GEMM:  C = act(X @ W^T + bias)
//   4 tiers (hh,hm,mh,mm); R12-verified numerically at output precision.
// k-loop (R11/R12-proven, session-best 595 us): barrier -> DMA-B issue ->
//   A-prefetch issue -> split-VALU (covers load latency) -> barrier -> MFMA.
// R15/R16 refuted occupancy levers INSIDE a dispatch; R18 hides vis1's
// latency by co-scheduling independent GEMMs in the SAME dispatch:
//   ROUTE=0: set = blockIdx.z, bn = blockIdx.y*BN (R12 behavior)
//   ROUTE=1: blockIdx.y<4 -> set0 (vis1, bn=y*BN); y==4 -> set1 (txt);
//            y==5 -> set2 (sen). txt/sen retire after K=512 and free CUs.
// Per-set runtime ldc/nreal/K. LDS 32KB at <128,128> (3 blocks/CU, MINW=3).
// LDS swizzle (verified R3: SQ_LDS_BANK_CONFLICT = 0): us16 idx =
//   row*32 + ((slot8 ^ ((row>>1)&3))*8 + e); A swizzled write+read;
//   B linear DMA dest + pre-swizzled global source col + swizzled read.
// OUT: 0 = relu; 1 = tanh with col<nreal store guard.
// 256 threads = 4 waves, 2x2 wave grid; wave tile (BM/2)x(BN/2).
// ---------------------------------------------------------------------------
template<int BM, int BN, int OUT, int MINW, int ROUTE>
__global__ __launch_bounds__(256, MINW)
void gemm_split(const float* X0, int ldx0, const us16* Bh0, const us16* Bm0,
                const float* bias0, float* C0, int ldc0, int nreal0, int K0,
                const float* X1, int ldx1, const us16* Bh1, const us16* Bm1,
                const float* bias1, float* C1, int ldc1, int nreal1, int K1,
                const float* X2, int ldx2, const us16* Bh2, const us16* Bm2,
                const float* bias2, float* C2, int ldc2, int nreal2, int K2)
{
    constexpr int MT  = BM / 32;      // 16-row m-tiles per wave
    constexpr int NT  = BN / 32;      // 16-col n-tiles per wave
    constexpr int NF4 = BM / 32;      // float4 A-loads per thread per k-tile
    constexpr int LB  = BN / 64;      // B DMA chunks per wave per plane

    int set, bnIdx;
    if (ROUTE == 0) { set = blockIdx.z; bnIdx = blockIdx.y; }
    else {
        if (blockIdx.y < 4) { set = 0; bnIdx = blockIdx.y; }
        else                { set = blockIdx.y - 3; bnIdx = 0; }
    }
    const float* X; int ldx; const us16 *Bh, *Bm; const float* bias;
    float* C; int ldc, nreal, K;
    if (set == 0)      { X = X0; ldx = ldx0; Bh = Bh0; Bm = Bm0; bias = bias0; C = C0; ldc = ldc0; nreal = nreal0; K = K0; }
    else if (set == 1) { X = X1; ldx = ldx1; Bh = Bh1; Bm = Bm1; bias = bias1; C = C1; ldc = ldc1; nreal = nreal1; K = K1; }
    else               { X = X2; ldx = ldx2; Bh = Bh2; Bm = Bm2; bias = bias2; C = C2; ldc = ldc2; nreal = nreal2; K = K2; }

    alignas(16) __shared__ us16 lds[(BM + BN) * 64];
    us16* AsH = lds;
    us16* AsM = lds + BM * 32;
    us16* BsH = lds + BM * 64;
    us16* BsM = lds + BM * 64 + BN * 32;

    const int tid  = threadIdx.x;
    const int lane = tid & 63;
    const int wid  = tid >> 6;
    const int bm   = blockIdx.x * BM;
    const int bn   = bnIdx * BN;
    const int lm   = lane & 15;       // fragment row/col within 16
    const int kb   = lane >> 4;       // k-quad 0..3
    const int wm   = (wid >> 1) * (BM / 2);
    const int wn   = (wid & 1) * (BN / 2);

    // A staging map: thread covers rows arow + i*32, cols acol..acol+3
    const int arow = tid >> 3;        // 0..31
    const int acol = (tid & 7) * 4;   // 0,4,..,28
    const int asw  = ((arow >> 1) & 3) << 3;   // A write swizzle (us16 idx bits 3-4)
    const int fsw  = ((lm >> 1) & 3) << 3;     // fragment read swizzle

    f32x4 acc[MT][NT];
#pragma unroll
    for (int i = 0; i < MT; ++i)
#pragma unroll
        for (int j = 0; j < NT; ++j) acc[i][j] = (f32x4){0.f, 0.f, 0.f, 0.f};

    float4 pref[NF4];
#pragma unroll
    for (int i = 0; i < NF4; ++i)
        pref[i] = *(const float4*)(X + (size_t)(bm + i * 32 + arow) * ldx + acol);

    // B DMA: linear dest (wave-uniform base + lane*16B), pre-swizzled src col
    const int bcol = ((lane & 3) ^ ((lane >> 3) & 3)) * 8;

    for (int k0 = 0; k0 < K; k0 += 32) {
        __syncthreads();   // previous compute done; LDS reusable
        // ---- hoisted: async DMA B tile (2 planes) — flies under the split ----
#pragma unroll
        for (int q = 0; q < LB; ++q) {
            const int rb = wid * (LB * 16) + q * 16;          // wave-uniform
            const int gr = bn + rb + (lane >> 2);
            const int gc = k0 + bcol;
            dma16(Bh + (size_t)gr * K + gc, &BsH[rb * 32]);
            dma16(Bm + (size_t)gr * K + gc, &BsM[rb * 32]);
        }
        // ---- hoisted: A prefetch for next k-tile (ping-pong regs) ----
        float4 prefN[NF4];
        if (k0 + 32 < K) {
#pragma unroll
            for (int i = 0; i < NF4; ++i)
                prefN[i] = *(const float4*)(X + (size_t)(bm + i * 32 + arow) * ldx
                                            + (k0 + 32) + acol);
        }
        // ---- split current A into h/m LDS planes (covers load latency) ----
#pragma unroll
        for (int i = 0; i < NF4; ++i) {
            const int r = i * 32 + arow;
            uint2 h, m;
            split2pk(pref[i], h, m);
            *(uint2*)&AsH[r * 32 + (acol ^ asw)] = h;
            *(uint2*)&AsM[r * 32 + (acol ^ asw)] = m;
        }
        if (k0 + 32 < K) {
#pragma unroll
            for (int i = 0; i < NF4; ++i) pref[i] = prefN[i];
        }
        __syncthreads();   // staging visible (compiler drains vmcnt+lgkm)

        // ---- MFMA phase: 4 tiers (hh, hm, mh, mm) ----
        s16x8 ah[MT], am[MT];
#pragma unroll
        for (int mt = 0; mt < MT; ++mt) {
            const int off = (wm + mt * 16 + lm) * 32 + (kb * 8 ^ fsw);
            ah[mt] = *(const s16x8*)&AsH[off];
            am[mt] = *(const s16x8*)&AsM[off];
        }
#pragma unroll
        for (int nt = 0; nt < NT; ++nt) {
            const int off = (wn + nt * 16 + lm) * 32 + (kb * 8 ^ fsw);
            s16x8 bfh = *(const s16x8*)&BsH[off];
            s16x8 bfm = *(const s16x8*)&BsM[off];
#pragma unroll
            for (int mt = 0; mt < MT; ++mt) {
                acc[mt][nt] = mfma16(ah[mt], bfh, acc[mt][nt]);
                acc[mt][nt] = mfma16(ah[mt], bfm, acc[mt][nt]);
                acc[mt][nt] = mfma16(am[mt], bfh, acc[mt][nt]);
                acc[mt][nt] = mfma16(am[mt], bfm, acc[mt][nt]);
            }
        }
    }

    // ---- epilogue: bias + activation (C/D map: col=lane&15, row=quad*4+r) ----
    float bv[NT];
#pragma unroll
    for (int nt = 0; nt < NT; ++nt) {
        const int col = bn + wn + nt * 16 + lm;
        bv[nt] = (col < nreal) ? bias[col] : 0.f;
    }
#pragma unroll
    for (int nt = 0; nt < NT; ++nt) {
        const int col = bn + wn + nt * 16 + lm;
#pragma unroll
        for (int mt = 0; mt < MT; ++mt) {
#pragma unroll
            for (int r = 0; r < 4; ++r) {
                const int row = bm + wm + mt * 16 + kb * 4 + r;
                float v = acc[mt][nt][r] + bv[nt];
                if (OUT == 0) {
                    C[(size_t)row * ldc + col] = fmaxf(v, 0.f);
                } else {
                    if (col < nreal)
                        C[(size_t)row * ldc + col] = tanhf(v);
                }
            }
        }
    }
}

// ---------------------------------------------------------------------------
// Weight pre-split into padded bf16 hi/mid/lo planes (lo unused by gemm).
// Plane layout (ushort offsets): w1v [512x2048] @0, w1t @1048576, w1s @1114112,
// w2v @1179648, wfp [256x416 pad] @1245184, wfc [64x256 pad] @1351680; tot 1368064
// ---------------------------------------------------------------------------
#define WOFF_W1T 1048576
#define WOFF_W1S 1114112
#define WOFF_W2V 1179648
#define WOFF_WFP 1245184
#define WOFF_WFC 1351680
#define WTOT     1368064

__global__ void split_weights(const float* __restrict__ w1v, const float* __restrict__ w1t,
                              const float* __restrict__ w1s, const float* __restrict__ w2v,
                              const float* __restrict__ wfp, const float* __restrict__ wfc,
                              us16* __restrict__ hi, us16* __restrict__ mi,
                              us16* __restrict__ lo)
{
    int idx = blockIdx.x * 256 + threadIdx.x;
    if (idx >= WTOT) return;
    const float* src; int N, K, Kp; int local;
    if (idx < WOFF_W1T)      { src = w1v; N = 512; K = 2048; Kp = 2048; local = idx; }
    else if (idx < WOFF_W1S) { src = w1t; N = 128; K = 512;  Kp = 512;  local = idx - WOFF_W1T; }
    else if (idx < WOFF_W2V) { src = w1s; N = 128; K = 512;  Kp = 512;  local = idx - WOFF_W1S; }
    else if (idx < WOFF_WFP) { src = w2v; N = 128; K = 512;  Kp = 512;  local = idx - WOFF_W2V; }
    else if (idx < WOFF_WFC) { src = wfp; N = 256; K = 388;  Kp = 416;  local = idx - WOFF_WFP; }
    else                     { src = wfc; N = 36;  K = 256;  Kp = 256;  local = idx - WOFF_WFC; }
    int n = local / Kp, k = local % Kp;
    float v = (n < N && k < K) ? src[(size_t)n * K + k] : 0.f;
    us16 h, m, l;
    split3(v, h, m, l);
    hi[idx] = h; mi[idx] = m; lo[idx] = l;
}

// ---------------------------------------------------------------------------
// pos branch + cat K-padding: cat cols [256,260) = relu(pos), [388,416) = 0
// ---------------------------------------------------------------------------
__global__ void pos_pad(const float* __restrict__ seq, float* __restrict__ cat)
{
    int idx = blockIdx.x * 256 + threadIdx.x;
    if (idx >= MROWS * 32) return;
    int row = idx >> 5, j = idx & 31;
    if (j < 4) {
        float v = seq[(size_t)row * 3076 + 2560 + j];
        cat[(size_t)row * 416 + 256 + j] = fmaxf(v, 0.f);
    } else {
        cat[(size_t)row * 416 + 388 + (j - 4)] = 0.f;
    }
}

// ---------------------------------------------------------------------------
// Sinkhorn (verified in R2)
// ---------------------------------------------------------------------------
__global__ __launch_bounds__(256)
void sinkhorn_kernel(const float* __restrict__ Z, float* __restrict__ out)
{
    __shared__ float A[NMAT][NMAT + 1];
    __shared__ float lse[NMAT];
    const int b = blockIdx.x;
    const int tid = threadIdx.x;
    const float* zb = Z + (size_t)b * NMAT * NMAT;

    for (int idx = tid; idx < NMAT * NMAT; idx += 256)
        A[idx / NMAT][idx % NMAT] = expf(zb[idx] * TAU_INV);
    __syncthreads();

    for (int it = 0; it < 20; ++it) {
        if (tid < NMAT * 4) {
            int r = tid >> 2, g = tid & 3;
            float m = -3.402823466e38f;
            for (int j = g; j < NMAT; j += 4) m = fmaxf(m, A[r][j]);
            m = fmaxf(m, __shfl_xor(m, 2, 4));
            m = fmaxf(m, __shfl_xor(m, 1, 4));
            float s = 0.f;
            for (int j = g; j < NMAT; j += 4) s += expf(A[r][j] - m);
            s += __shfl_xor(s, 2, 4);
            s += __shfl_xor(s, 1, 4);
            if (g == 0) lse[r] = m + logf(s);
        }
        __syncthreads();
        for (int idx = tid; idx < NMAT * NMAT; idx += 256)
            A[idx / NMAT][idx % NMAT] -= lse[idx / NMAT];
        __syncthreads();

        if (tid < NMAT * 4) {
            int c = tid >> 2, g = tid & 3;
            float m = -3.402823466e38f;
            for (int i = g; i < NMAT; i += 4) m = fmaxf(m, A[i][c]);
            m = fmaxf(m, __shfl_xor(m, 2, 4));
            m = fmaxf(m, __shfl_xor(m, 1, 4));
            float s = 0.f;
            for (int i = g; i < NMAT; i += 4) s += expf(A[i][c] - m);
            s += __shfl_xor(s, 2, 4);
            s += __shfl_xor(s, 1, 4);
            if (g == 0) lse[c] = m + logf(s);
        }
        __syncthreads();
        for (int idx = tid; idx < NMAT * NMAT; idx += 256)
            A[idx / NMAT][idx % NMAT] -= lse[idx % NMAT];
        __syncthreads();
    }

    for (int idx = tid; idx < NMAT * NMAT; idx += 256)
        out[(size_t)b * NMAT * NMAT + idx] = expf(A[idx / NMAT][idx % NMAT]);
}

// ---------------------------------------------------------------------------
extern "C" void kernel_launch(void* const* d_in, const int* in_sizes, int n_in,
                              void* d_out, int out_size, void* d_ws, size_t ws_size,
                              hipStream_t stream)
{
    const float* seq = (const float*)d_in[0];
    const float* W1t = (const float*)d_in[1];
    const float* b1t = (const float*)d_in[2];
    const float* W1v = (const float*)d_in[3];
    const float* b1v = (const float*)d_in[4];
    const float* W2v = (const float*)d_in[5];
    const float* b2v = (const float*)d_in[6];
    const float* W1s = (const float*)d_in[7];
    const float* b1s = (const float*)d_in[8];
    const float* Wfp = (const float*)d_in[9];
    const float* bfp = (const float*)d_in[10];
    const float* Wfc = (const float*)d_in[11];
    const float* bfc = (const float*)d_in[12];

    float* wsF = (float*)d_ws;
    dim3 blk(256);

    // Full-M layout needs 76.63 MB (R9-R17 verified working); fallback otherwise.
    const bool full = ws_size >= (size_t)19156992 * 4;

    if (full) {
        // ws layout (float offsets), full-M:
        //   [0, 9437184)         : vis1 (18432x512); later h256 (18432x256)
        //   [9437184, 17104896)  : cat (18432x416); later logits
        //   [17104896, +2052096) : weight planes hi/mid/lo (3 x WTOT us16)
        float* vis1buf = wsF;
        float* h256    = wsF;
        float* cat     = wsF + 9437184;
        float* logits  = wsF + 9437184;
        us16*  Whi     = (us16*)(wsF + 17104896);
        us16*  Wmi     = Whi + WTOT;
        us16*  Wlo     = Wmi + WTOT;

        split_weights<<<dim3((WTOT + 255) / 256), blk, 0, stream>>>(
            W1v, W1t, W1s, W2v, Wfp, Wfc, Whi, Wmi, Wlo);
        pos_pad<<<dim3((MROWS * 32 + 255) / 256), blk, 0, stream>>>(seq, cat);
        // MEGA: vis1 (y=0..3) + txt (y=4) + sen (y=5) in ONE dispatch (R18).
        // 864 blocks of <128,128>; txt/sen finish at K=512 and free CUs to
        // vis1's tail — hides part of vis1's structural latency.
        gemm_split<128, 128, 0, 3, 1><<<dim3(MROWS / 128, 6, 1), blk, 0, stream>>>(
            seq + 512,  3076, Whi,            Wmi,            b1v, vis1buf, 512, 512, 2048,
            seq,        3076, Whi + WOFF_W1T, Wmi + WOFF_W1T, b1t, cat,     416, 128, 512,
            seq + 2564, 3076, Whi + WOFF_W1S, Wmi + WOFF_W1S, b1s, cat + 260, 416, 128, 512);
        // vis2: BN=64, y=2 -> 576 blocks (16 KB LDS)
        gemm_split<64, 64, 0, 4, 0><<<dim3(MROWS / 64, 2, 1), blk, 0, stream>>>(
            vis1buf, 512, Whi + WOFF_W2V, Wmi + WOFF_W2V, b2v, cat + 128, 416, 128, 512,
            vis1buf, 512, Whi + WOFF_W2V, Wmi + WOFF_W2V, b2v, cat + 128, 416, 128, 512,
            vis1buf, 512, Whi + WOFF_W2V, Wmi + WOFF_W2V, b2v, cat + 128, 416, 128, 512);
        // fc_pos: (M,416)->256 relu -> h256 (overlays vis1buf, now dead)
        gemm_split<64, 128, 0, 4, 0><<<dim3(MROWS / 64, 2, 1), blk, 0, stream>>>(
            cat, 416, Whi + WOFF_WFP, Wmi + WOFF_WFP, bfp, h256, 256, 256, 416,
            cat, 416, Whi + WOFF_WFP, Wmi + WOFF_WFP, bfp, h256, 256, 256, 416,
            cat, 416, Whi + WOFF_WFP, Wmi + WOFF_WFP, bfp, h256, 256, 256, 416);
        // fc: (M,256)->36 tanh -> logits (overlays cat, now dead)
        gemm_split<64, 64, 1, 4, 0><<<dim3(MROWS / 64, 1, 1), blk, 0, stream>>>(
            h256, 256, Whi + WOFF_WFC, Wmi + WOFF_WFC, bfc, logits, 36, 36, 256,
            h256, 256, Whi + WOFF_WFC, Wmi + WOFF_WFC, bfc, logits, 36, 36, 256,
            h256, 256, Whi + WOFF_WFC, Wmi + WOFF_WFC, bfc, logits, 36, 36, 256);
        sinkhorn_kernel<<<dim3(BATCH), blk, 0, stream>>>(logits, (float*)d_out);
    } else {
        // ---- half-M fallback (57.8 MB), same 2-plane kernel, ROUTE=0 ----
        float* vis1buf = wsF;
        float* h256    = wsF;
        float* cat     = wsF + 4718592;
        float* logits  = wsF + 4718592;
        us16*  Whi     = (us16*)(wsF + 12386304);
        us16*  Wmi     = Whi + WTOT;
        us16*  Wlo     = Wmi + WTOT;

        split_weights<<<dim3((WTOT + 255) / 256), blk, 0, stream>>>(
            W1v, W1t, W1s, W2v, Wfp, Wfc, Whi, Wmi, Wlo);
        pos_pad<<<dim3((MROWS * 32 + 255) / 256), blk, 0, stream>>>(seq, cat);
        gemm_split<64, 128, 0, 4, 0><<<dim3(MROWS / 64, 1, 2), blk, 0, stream>>>(
            seq,        3076, Whi + WOFF_W1T, Wmi + WOFF_W1T, b1t, cat,       416, 128, 512,
            seq + 2564, 3076, Whi + WOFF_W1S, Wmi + WOFF_W1S, b1s, cat + 260, 416, 128, 512,
            seq,        3076, Whi + WOFF_W1T, Wmi + WOFF_W1T, b1t, cat,       416, 128, 512);
        for (int h = 0; h < 2; ++h) {
            const float* xh = seq + 512 + (size_t)h * MHALF * 3076;
            float* ch = cat + 128 + (size_t)h * MHALF * 416;
            gemm_split<128, 128, 0, 3, 0><<<dim3(MHALF / 128, 4, 1), blk, 0, stream>>>(
                xh, 3076, Whi, Wmi, b1v, vis1buf, 512, 512, 2048,
                xh, 3076, Whi, Wmi, b1v, vis1buf, 512, 512, 2048,
                xh, 3076, Whi, Wmi, b1v, vis1buf, 512, 512, 2048);
            gemm_split<64, 64, 0, 4, 0><<<dim3(MHALF / 64, 2, 1), blk, 0, stream>>>(
                vis1buf, 512, Whi + WOFF_W2V, Wmi + WOFF_W2V, b2v, ch, 416, 128, 512,
                vis1buf, 512, Whi + WOFF_W2V, Wmi + WOFF_W2V, b2v, ch, 416, 128, 512,
                vis1buf, 512, Whi + WOFF_W2V, Wmi + WOFF_W2V, b2v, ch, 416, 128, 512);
        }
        gemm_split<64, 128, 0, 4, 0><<<dim3(MROWS / 64, 2, 1), blk, 0, stream>>>(
            cat, 416, Whi + WOFF_WFP, Wmi + WOFF_WFP, bfp, h256, 256, 256, 416,
            cat, 416, Whi + WOFF_WFP, Wmi + WOFF_WFP, bfp, h256, 256, 256, 416,
            cat, 416, Whi + WOFF_WFP, Wmi + WOFF_WFP, bfp, h256, 256, 256, 416);
        gemm_split<64, 64, 1, 4, 0><<<dim3(MROWS / 64, 1, 1), blk, 0, stream>>>(
            h256, 256, Whi + WOFF_WFC, Wmi + WOFF_WFC, bfc, logits, 36, 36, 256,
            h256, 256, Whi + WOFF_WFC, Wmi + WOFF_WFC, bfc, logits, 36, 36, 256,
            h256, 256, Whi + WOFF_WFC, Wmi + WOFF_WFC, bfc, logits, 36, 36, 256);
        sinkhorn_kernel<<<dim3(BATCH), blk, 0, stream>>>(logits, (float*)d_out);
    }
}